// Round 14
// baseline (686.523 us; speedup 1.0000x reference)
//
#include <hip/hip_runtime.h>

typedef __bf16 bf16;
typedef __bf16 bf16x8 __attribute__((ext_vector_type(8)));
typedef float f32x4 __attribute__((ext_vector_type(4)));

#define MFMA16(a, b, c) __builtin_amdgcn_mfma_f32_16x16x32_bf16((a), (b), (c), 0, 0, 0)

static __device__ __forceinline__ bf16x8 ldg8(const bf16* p) {
  return *(const bf16x8*)p;
}

// ===========================================================================
// Established: 5 fp32 inputs, FP32 output, ws >= 44 MB (r10 ran 44MB layout).
// r11 PASS 675us (flash 474us, wave-count capped at 4096). r12/r13 intra-block
// KV-split: bit-identical deterministic FAIL (0.185) — combine-in-LDS design
// unexplained after full audit; abandoned. This round: GRID-level KV split —
// single-wave blocks, r11's exact loop body, raw (o,l) partials to global,
// trivial combine kernel. 8192 waves -> occupancy cap 100%. ws<61.4MB falls
// back to exact r11 flash (both paths correct).
// ===========================================================================

__global__ __launch_bounds__(256) void cvt_x(const float* __restrict__ src,
                                             bf16* __restrict__ dst) {
  int i = (blockIdx.x * 256 + threadIdx.x) * 4;
#pragma unroll
  for (int j = 0; j < 4; j++) dst[i + j] = (bf16)src[i + j];
}

__global__ __launch_bounds__(256) void transpose64(const float* __restrict__ W,
                                                   bf16* __restrict__ Wt,
                                                   int K, int N) {
  __shared__ bf16 tile[64][65];
  int k0 = blockIdx.x * 64, n0 = blockIdx.y * 64;
  int c = threadIdx.x & 63;
  int r4 = threadIdx.x >> 6;
#pragma unroll
  for (int i = 0; i < 16; i++) {
    int r = r4 * 16 + i;
    tile[r][c] = (bf16)W[(size_t)(k0 + r) * N + n0 + c];
  }
  __syncthreads();
#pragma unroll
  for (int i = 0; i < 16; i++) {
    int r = r4 * 16 + i;
    Wt[(size_t)(n0 + r) * K + k0 + c] = tile[c][r];
  }
}

// ---------------------------------------------------------------------------
// GEMM core: one wave = 16(M) x 64(N) strip. A [M][K] row-major; Bt [N][K].
// MFMA 16x16x32 layouts (m89/m91): A a[j]=A[l16][quad*8+j];
// B b[j]=Bt[n][quad*8+j]; C acc[r]=C[quad*4+r][l16].
// ---------------------------------------------------------------------------
__device__ __forceinline__ void gemm_acc_16x64(const bf16* __restrict__ Arow,
                                               const bf16* __restrict__ Bt,
                                               int n0, int Kdim, int l16,
                                               int quad, f32x4 acc[4]) {
#pragma unroll 4
  for (int k0 = 0; k0 < Kdim; k0 += 32) {
    bf16x8 a = ldg8(Arow + k0 + quad * 8);
#pragma unroll
    for (int ct = 0; ct < 4; ct++) {
      bf16x8 b = ldg8(Bt + (size_t)(n0 + ct * 16 + l16) * Kdim + k0 + quad * 8);
      acc[ct] = MFMA16(a, b, acc[ct]);
    }
  }
}

__global__ __launch_bounds__(256) void qkv_gemm(const bf16* __restrict__ X,
                                                const bf16* __restrict__ Wt1,
                                                const float* __restrict__ bqkv,
                                                bf16* __restrict__ Q,
                                                bf16* __restrict__ Kh,
                                                bf16* __restrict__ Vt) {
  int m0 = blockIdx.x * 64, n0 = blockIdx.y * 64;
  int wave = threadIdx.x >> 6, lane = threadIdx.x & 63;
  int l16 = lane & 15, quad = lane >> 4;

  f32x4 acc[4] = {};
  const bf16* Arow = X + (size_t)(m0 + wave * 16 + l16) * 512;
  gemm_acc_16x64(Arow, Wt1, n0, 512, l16, quad, acc);

#pragma unroll
  for (int ct = 0; ct < 4; ct++) {
    int c = n0 + ct * 16 + l16;
    float bias = bqkv[c];
    int which = c >> 9, inner = c & 511;
    int h = inner >> 6, d = inner & 63;
#pragma unroll
    for (int r = 0; r < 4; r++) {
      int m = m0 + wave * 16 + quad * 4 + r;
      int b = m >> 12, n = m & 4095;
      int bh = b * 8 + h;
      bf16 v = (bf16)(acc[ct][r] + bias);
      if (which == 0)
        Q[((size_t)bh * 4096 + n) * 64 + d] = v;
      else if (which == 1)
        Kh[((size_t)bh * 4096 + n) * 64 + d] = v;
      else
        Vt[((size_t)bh * 64 + d) * 4096 + n] = v;
    }
  }
}

// ---------------------------------------------------------------------------
// flash_partial: grid (256 strips, 16 bh, 2 halves), block 64 = ONE wave.
// r11's exact loop body over KV [half*2048, half*2048+2048). Constant-max
// softmax. Writes raw o (bf16, 16x64) and l (fp32, 16) partials per unit.
// ---------------------------------------------------------------------------
__global__ __launch_bounds__(64) void flash_partial(const bf16* __restrict__ Q,
                                                    const bf16* __restrict__ K,
                                                    const bf16* __restrict__ Vt,
                                                    bf16* __restrict__ Opart,
                                                    float* __restrict__ Lpart) {
  int strip = blockIdx.x, bh = blockIdx.y, half = blockIdx.z;
  int lane = threadIdx.x;
  int l16 = lane & 15, quad = lane >> 4;

  const bf16* Qh = Q + (size_t)bh * 4096 * 64;
  const bf16* Kh = K + (size_t)bh * 4096 * 64;
  const bf16* Vh = Vt + (size_t)bh * 64 * 4096;

  int qrow = strip * 16;
  bf16x8 aq0 = ldg8(Qh + (size_t)(qrow + l16) * 64 + quad * 8);
  bf16x8 aq1 = ldg8(Qh + (size_t)(qrow + l16) * 64 + 32 + quad * 8);

  f32x4 o[4] = {};
  float l_lane[4] = {0.f, 0.f, 0.f, 0.f};

  __shared__ __align__(16) bf16 P[16][72];

  int kv0 = half * 2048;
  for (int kb = kv0; kb < kv0 + 2048; kb += 64) {
    f32x4 s[4] = {};
#pragma unroll
    for (int ct = 0; ct < 4; ct++) {
      const bf16* kr = Kh + (size_t)(kb + ct * 16 + l16) * 64;
      bf16x8 b0 = ldg8(kr + quad * 8);
      bf16x8 b1 = ldg8(kr + 32 + quad * 8);
      s[ct] = MFMA16(aq0, b0, s[ct]);
      s[ct] = MFMA16(aq1, b1, s[ct]);
    }
#pragma unroll
    for (int ct = 0; ct < 4; ct++) {
#pragma unroll
      for (int r = 0; r < 4; r++) {
        float p = __expf(s[ct][r] * 0.125f);
        l_lane[r] += p;
        P[quad * 4 + r][ct * 16 + l16] = (bf16)p;
      }
    }
    bf16x8 ap0 = ldg8(&P[l16][quad * 8]);
    bf16x8 ap1 = ldg8(&P[l16][32 + quad * 8]);
#pragma unroll
    for (int ct = 0; ct < 4; ct++) {
      const bf16* vr = Vh + (size_t)(ct * 16 + l16) * 4096 + kb;
      bf16x8 bv0 = ldg8(vr + quad * 8);
      bf16x8 bv1 = ldg8(vr + 32 + quad * 8);
      o[ct] = MFMA16(ap0, bv0, o[ct]);
      o[ct] = MFMA16(ap1, bv1, o[ct]);
    }
  }

  float lrow[4];
#pragma unroll
  for (int r = 0; r < 4; r++) {
    float l = l_lane[r];
#pragma unroll
    for (int off = 1; off < 16; off <<= 1) l += __shfl_xor(l, off);
    lrow[r] = l;
  }

  size_t unit = ((size_t)half * 16 + bh) * 256 + strip;
  bf16* op = Opart + unit * 1024;
#pragma unroll
  for (int ct = 0; ct < 4; ct++)
#pragma unroll
    for (int r = 0; r < 4; r++)
      op[(quad * 4 + r) * 64 + ct * 16 + l16] = (bf16)o[ct][r];
  if (l16 == 0) {
#pragma unroll
    for (int r = 0; r < 4; r++) Lpart[unit * 16 + quad * 4 + r] = lrow[r];
  }
}

// ---------------------------------------------------------------------------
// flash_combine: AO = (o0+o1)/(l0+l1). Grid (256, 16), block 256.
// ---------------------------------------------------------------------------
__global__ __launch_bounds__(256) void flash_combine(const bf16* __restrict__ Opart,
                                                     const float* __restrict__ Lpart,
                                                     bf16* __restrict__ AO) {
  int strip = blockIdx.x, bh = blockIdx.y;
  int col = threadIdx.x & 63;
  int rbase = (threadIdx.x >> 6) * 4;
  size_t u0 = (size_t)bh * 256 + strip;
  size_t u1 = ((size_t)16 + bh) * 256 + strip;
  int b = bh >> 3, h = bh & 7;
#pragma unroll
  for (int i = 0; i < 4; i++) {
    int row = rbase + i;
    float o0 = (float)Opart[u0 * 1024 + row * 64 + col];
    float o1 = (float)Opart[u1 * 1024 + row * 64 + col];
    float lsum = Lpart[u0 * 16 + row] + Lpart[u1 * 16 + row];
    int n = strip * 16 + row;
    AO[((size_t)(b * 4096 + n)) * 512 + h * 64 + col] = (bf16)((o0 + o1) / lsum);
  }
}

// ---------------------------------------------------------------------------
// Fallback: r11's exact flash (PASS at 675us). Grid (64,16), block 256.
// ---------------------------------------------------------------------------
__global__ __launch_bounds__(256) void flash_attn_r11(const bf16* __restrict__ Q,
                                                      const bf16* __restrict__ K,
                                                      const bf16* __restrict__ Vt,
                                                      bf16* __restrict__ AO) {
  int qt = blockIdx.x, bh = blockIdx.y;
  int wave = threadIdx.x >> 6, lane = threadIdx.x & 63;
  int l16 = lane & 15, quad = lane >> 4;

  const bf16* Qh = Q + (size_t)bh * 4096 * 64;
  const bf16* Kh = K + (size_t)bh * 4096 * 64;
  const bf16* Vh = Vt + (size_t)bh * 64 * 4096;

  int qrow = qt * 64 + wave * 16;
  bf16x8 aq0 = ldg8(Qh + (size_t)(qrow + l16) * 64 + quad * 8);
  bf16x8 aq1 = ldg8(Qh + (size_t)(qrow + l16) * 64 + 32 + quad * 8);

  f32x4 o[4] = {};
  float l_lane[4] = {0.f, 0.f, 0.f, 0.f};
  __shared__ __align__(16) bf16 P[4][16][72];

  for (int kb = 0; kb < 4096; kb += 64) {
    f32x4 s[4] = {};
#pragma unroll
    for (int ct = 0; ct < 4; ct++) {
      const bf16* kr = Kh + (size_t)(kb + ct * 16 + l16) * 64;
      bf16x8 b0 = ldg8(kr + quad * 8);
      bf16x8 b1 = ldg8(kr + 32 + quad * 8);
      s[ct] = MFMA16(aq0, b0, s[ct]);
      s[ct] = MFMA16(aq1, b1, s[ct]);
    }
#pragma unroll
    for (int ct = 0; ct < 4; ct++) {
#pragma unroll
      for (int r = 0; r < 4; r++) {
        float p = __expf(s[ct][r] * 0.125f);
        l_lane[r] += p;
        P[wave][quad * 4 + r][ct * 16 + l16] = (bf16)p;
      }
    }
    bf16x8 ap0 = ldg8(&P[wave][l16][quad * 8]);
    bf16x8 ap1 = ldg8(&P[wave][l16][32 + quad * 8]);
#pragma unroll
    for (int ct = 0; ct < 4; ct++) {
      const bf16* vr = Vh + (size_t)(ct * 16 + l16) * 4096 + kb;
      bf16x8 bv0 = ldg8(vr + quad * 8);
      bf16x8 bv1 = ldg8(vr + 32 + quad * 8);
      o[ct] = MFMA16(ap0, bv0, o[ct]);
      o[ct] = MFMA16(ap1, bv1, o[ct]);
    }
  }

  float inv[4];
#pragma unroll
  for (int r = 0; r < 4; r++) {
    float l = l_lane[r];
#pragma unroll
    for (int off = 1; off < 16; off <<= 1) l += __shfl_xor(l, off);
    inv[r] = 1.0f / l;
  }

  int b = bh >> 3, h = bh & 7;
#pragma unroll
  for (int r = 0; r < 4; r++) {
    int n = qrow + quad * 4 + r;
#pragma unroll
    for (int ct = 0; ct < 4; ct++) {
      AO[((size_t)(b * 4096 + n)) * 512 + h * 64 + ct * 16 + l16] =
          (bf16)(o[ct][r] * inv[r]);
    }
  }
}

// ---------------------------------------------------------------------------
// Output projection -> FP32 out.
// ---------------------------------------------------------------------------
__global__ __launch_bounds__(256) void out_gemm(const bf16* __restrict__ AO,
                                                const bf16* __restrict__ Wt2,
                                                const float* __restrict__ bout,
                                                float* __restrict__ Out) {
  int m0 = blockIdx.x * 64, n0 = blockIdx.y * 64;
  int wave = threadIdx.x >> 6, lane = threadIdx.x & 63;
  int l16 = lane & 15, quad = lane >> 4;

  f32x4 acc[4] = {};
  const bf16* Arow = AO + (size_t)(m0 + wave * 16 + l16) * 512;
  gemm_acc_16x64(Arow, Wt2, n0, 512, l16, quad, acc);

#pragma unroll
  for (int ct = 0; ct < 4; ct++) {
    int c = n0 + ct * 16 + l16;
    float bias = bout[c];
#pragma unroll
    for (int r = 0; r < 4; r++) {
      int m = m0 + wave * 16 + quad * 4 + r;
      Out[(size_t)m * 512 + c] = acc[ct][r] + bias;
    }
  }
}

// ---------------------------------------------------------------------------
// ws: Q 0 | K 8388608 | Vt 16777216 | AObf 25165824 | Wt1 33554432 |
//     Wt2 35127296 | Xb 35651584 | Opart 44040192 (16.8MB) |
//     Lpart 60817408 (0.5MB) | end 61341696
// ---------------------------------------------------------------------------
extern "C" void kernel_launch(void* const* d_in, const int* in_sizes, int n_in,
                              void* d_out, int out_size, void* d_ws,
                              size_t ws_size, hipStream_t stream) {
  const float* x = (const float*)d_in[0];
  const float* w_qkv = (const float*)d_in[1];
  const float* b_qkv = (const float*)d_in[2];
  const float* w_out = (const float*)d_in[3];
  const float* b_out = (const float*)d_in[4];
  float* out = (float*)d_out;

  char* ws = (char*)d_ws;
  bf16* Q = (bf16*)(ws + 0);
  bf16* K = (bf16*)(ws + 8388608);
  bf16* Vt = (bf16*)(ws + 16777216);
  bf16* AObf = (bf16*)(ws + 25165824);
  bf16* Wt1 = (bf16*)(ws + 33554432);
  bf16* Wt2 = (bf16*)(ws + 35127296);
  bf16* Xb = (bf16*)(ws + 35651584);
  bf16* Opart = (bf16*)(ws + 44040192);
  float* Lpart = (float*)(ws + 60817408);

  cvt_x<<<4096, 256, 0, stream>>>(x, Xb);
  transpose64<<<dim3(8, 24), 256, 0, stream>>>(w_qkv, Wt1, 512, 1536);
  transpose64<<<dim3(8, 8), 256, 0, stream>>>(w_out, Wt2, 512, 512);
  qkv_gemm<<<dim3(128, 24), 256, 0, stream>>>(Xb, Wt1, b_qkv, Q, K, Vt);
  if (ws_size >= 61341696) {
    flash_partial<<<dim3(256, 16, 2), 64, 0, stream>>>(Q, K, Vt, Opart, Lpart);
    flash_combine<<<dim3(256, 16), 256, 0, stream>>>(Opart, Lpart, AObf);
  } else {
    flash_attn_r11<<<dim3(64, 16), 256, 0, stream>>>(Q, K, Vt, AObf);
  }
  out_gemm<<<dim3(128, 8), 256, 0, stream>>>(AObf, Wt2, b_out, out);
}

// Round 15
// 364.849 us; speedup vs baseline: 1.8817x; 1.8817x over previous
//
#include <hip/hip_runtime.h>

typedef __bf16 bf16;
typedef __bf16 bf16x8 __attribute__((ext_vector_type(8)));
typedef float f32x4 __attribute__((ext_vector_type(4)));

#define MFMA16(a, b, c) __builtin_amdgcn_mfma_f32_16x16x32_bf16((a), (b), (c), 0, 0, 0)

static __device__ __forceinline__ bf16x8 ldg8(const bf16* p) {
  return *(const bf16x8*)p;
}

// ===========================================================================
// Established: 5 fp32 inputs, FP32 output, ws >= 61.4MB (r14 ran that layout).
// r11 474us / r14 479us flash invariant at 2x waves -> not latency-bound;
// theory: VMEM request fragmentation (16 x 64B segments per ldg8). This round:
// coalesced cooperative staging of contiguous K/V tiles into XOR-swizzled LDS
// (conflict-free write AND read), V re-laid out tiled [bh][tile][d][64].
// ===========================================================================

__global__ __launch_bounds__(256) void cvt_x(const float* __restrict__ src,
                                             bf16* __restrict__ dst) {
  int i = (blockIdx.x * 256 + threadIdx.x) * 4;
#pragma unroll
  for (int j = 0; j < 4; j++) dst[i + j] = (bf16)src[i + j];
}

__global__ __launch_bounds__(256) void transpose64(const float* __restrict__ W,
                                                   bf16* __restrict__ Wt,
                                                   int K, int N) {
  __shared__ bf16 tile[64][65];
  int k0 = blockIdx.x * 64, n0 = blockIdx.y * 64;
  int c = threadIdx.x & 63;
  int r4 = threadIdx.x >> 6;
#pragma unroll
  for (int i = 0; i < 16; i++) {
    int r = r4 * 16 + i;
    tile[r][c] = (bf16)W[(size_t)(k0 + r) * N + n0 + c];
  }
  __syncthreads();
#pragma unroll
  for (int i = 0; i < 16; i++) {
    int r = r4 * 16 + i;
    Wt[(size_t)(n0 + r) * K + k0 + c] = tile[c][r];
  }
}

// ---------------------------------------------------------------------------
// GEMM core (unchanged): one wave = 16(M) x 64(N) strip.
// ---------------------------------------------------------------------------
__device__ __forceinline__ void gemm_acc_16x64(const bf16* __restrict__ Arow,
                                               const bf16* __restrict__ Bt,
                                               int n0, int Kdim, int l16,
                                               int quad, f32x4 acc[4]) {
#pragma unroll 4
  for (int k0 = 0; k0 < Kdim; k0 += 32) {
    bf16x8 a = ldg8(Arow + k0 + quad * 8);
#pragma unroll
    for (int ct = 0; ct < 4; ct++) {
      bf16x8 b = ldg8(Bt + (size_t)(n0 + ct * 16 + l16) * Kdim + k0 + quad * 8);
      acc[ct] = MFMA16(a, b, acc[ct]);
    }
  }
}

// ---------------------------------------------------------------------------
// QKV projection. Q,K -> [bh][n][d]; V -> TILED [bh][n>>6][d][n&63]
// (so each 64-KV V-tile is one contiguous 8KB block for flash staging).
// ---------------------------------------------------------------------------
__global__ __launch_bounds__(256) void qkv_gemm(const bf16* __restrict__ X,
                                                const bf16* __restrict__ Wt1,
                                                const float* __restrict__ bqkv,
                                                bf16* __restrict__ Q,
                                                bf16* __restrict__ Kh,
                                                bf16* __restrict__ Vt) {
  int m0 = blockIdx.x * 64, n0 = blockIdx.y * 64;
  int wave = threadIdx.x >> 6, lane = threadIdx.x & 63;
  int l16 = lane & 15, quad = lane >> 4;

  f32x4 acc[4] = {};
  const bf16* Arow = X + (size_t)(m0 + wave * 16 + l16) * 512;
  gemm_acc_16x64(Arow, Wt1, n0, 512, l16, quad, acc);

#pragma unroll
  for (int ct = 0; ct < 4; ct++) {
    int c = n0 + ct * 16 + l16;
    float bias = bqkv[c];
    int which = c >> 9, inner = c & 511;
    int h = inner >> 6, d = inner & 63;
#pragma unroll
    for (int r = 0; r < 4; r++) {
      int m = m0 + wave * 16 + quad * 4 + r;
      int b = m >> 12, n = m & 4095;
      int bh = b * 8 + h;
      bf16 v = (bf16)(acc[ct][r] + bias);
      if (which == 0)
        Q[((size_t)bh * 4096 + n) * 64 + d] = v;
      else if (which == 1)
        Kh[((size_t)bh * 4096 + n) * 64 + d] = v;
      else
        Vt[(((size_t)bh * 64 + (n >> 6)) * 64 + d) * 64 + (n & 63)] = v;
    }
  }
}

// ---------------------------------------------------------------------------
// Flash attention v4: LDS-staged K/V tiles with XOR swizzle.
// Grid (64 q-tiles, 16 bh), block 256 = 4 waves, 16 Q rows/wave.
// Per tile: stage K (contig 8KB) + V (contig 8KB, tiled layout) with
// coalesced 1KB/instr loads; swizzle unit = row*8 + (c16 ^ (row&7)) gives
// conflict-free ds_write_b128 AND ds_read_b128 (bank math in journal).
// Constant-max softmax + per-wave P round-trip (proven r11).
// ---------------------------------------------------------------------------
__global__ __launch_bounds__(256) void flash_attn(const bf16* __restrict__ Q,
                                                  const bf16* __restrict__ K,
                                                  const bf16* __restrict__ Vt,
                                                  bf16* __restrict__ AO) {
  int qt = blockIdx.x, bh = blockIdx.y;
  int tid = threadIdx.x;
  int wave = tid >> 6, lane = tid & 63;
  int l16 = lane & 15, quad = lane >> 4;

  const bf16* Qh = Q + (size_t)bh * 4096 * 64;
  const bf16* Kh = K + (size_t)bh * 4096 * 64;
  const bf16* Vh = Vt + (size_t)bh * 64 * 4096;  // tiled [tile][d][64]

  __shared__ __align__(16) bf16 Klds[4096];  // [n][k], 16B-unit swizzled
  __shared__ __align__(16) bf16 Vlds[4096];  // [d][nn], swizzled
  __shared__ __align__(16) bf16 P[4][16][72];

  int qrow = qt * 64 + wave * 16;
  bf16x8 aq0 = ldg8(Qh + (size_t)(qrow + l16) * 64 + quad * 8);
  bf16x8 aq1 = ldg8(Qh + (size_t)(qrow + l16) * 64 + 32 + quad * 8);

  f32x4 o[4] = {};
  float l_lane[4] = {0.f, 0.f, 0.f, 0.f};

  for (int kb = 0; kb < 4096; kb += 64) {
    __syncthreads();  // previous tile's LDS reads complete
    const bf16* kg = Kh + (size_t)kb * 64;  // contiguous 8KB
    const bf16* vg = Vh + (size_t)kb * 64;  // contiguous 8KB (tiled layout)
#pragma unroll
    for (int rnd = 0; rnd < 2; rnd++) {
      int e = (rnd * 256 + tid) * 8;  // element offset 0..4095
      int row = e >> 6;
      int c16 = (e & 63) >> 3;
      int unit = row * 8 + (c16 ^ (row & 7));
      *(bf16x8*)&Klds[unit * 8] = ldg8(kg + e);
      *(bf16x8*)&Vlds[unit * 8] = ldg8(vg + e);
    }
    __syncthreads();  // staging visible to all waves

    // ---- S = Q K^T (B-frags from swizzled LDS) ----
    f32x4 s[4] = {};
#pragma unroll
    for (int ct = 0; ct < 4; ct++) {
      int n = ct * 16 + l16;
      bf16x8 b0 = *(const bf16x8*)&Klds[(n * 8 + (quad ^ (n & 7))) * 8];
      bf16x8 b1 = *(const bf16x8*)&Klds[(n * 8 + ((4 + quad) ^ (n & 7))) * 8];
      s[ct] = MFMA16(aq0, b0, s[ct]);
      s[ct] = MFMA16(aq1, b1, s[ct]);
    }
    // ---- p = exp(s/8); accumulate l; stage P (C-layout, per-wave) ----
#pragma unroll
    for (int ct = 0; ct < 4; ct++) {
#pragma unroll
      for (int r = 0; r < 4; r++) {
        float p = __expf(s[ct][r] * 0.125f);
        l_lane[r] += p;
        P[wave][quad * 4 + r][ct * 16 + l16] = (bf16)p;
      }
    }
    // ---- O += P V (A-frag from P, B-frag from swizzled Vlds) ----
    bf16x8 ap0 = ldg8(&P[wave][l16][quad * 8]);
    bf16x8 ap1 = ldg8(&P[wave][l16][32 + quad * 8]);
#pragma unroll
    for (int ct = 0; ct < 4; ct++) {
      int d = ct * 16 + l16;
      bf16x8 bv0 = *(const bf16x8*)&Vlds[(d * 8 + (quad ^ (d & 7))) * 8];
      bf16x8 bv1 = *(const bf16x8*)&Vlds[(d * 8 + ((4 + quad) ^ (d & 7))) * 8];
      o[ct] = MFMA16(ap0, bv0, o[ct]);
      o[ct] = MFMA16(ap1, bv1, o[ct]);
    }
  }

  // ---- one-time l reduction within each quad ----
  float inv[4];
#pragma unroll
  for (int r = 0; r < 4; r++) {
    float l = l_lane[r];
#pragma unroll
    for (int off = 1; off < 16; off <<= 1) l += __shfl_xor(l, off);
    inv[r] = 1.0f / l;
  }

  int b = bh >> 3, h = bh & 7;
#pragma unroll
  for (int r = 0; r < 4; r++) {
    int n = qrow + quad * 4 + r;
#pragma unroll
    for (int ct = 0; ct < 4; ct++) {
      AO[((size_t)(b * 4096 + n)) * 512 + h * 64 + ct * 16 + l16] =
          (bf16)(o[ct][r] * inv[r]);
    }
  }
}

// ---------------------------------------------------------------------------
// Output projection -> FP32 out.
// ---------------------------------------------------------------------------
__global__ __launch_bounds__(256) void out_gemm(const bf16* __restrict__ AO,
                                                const bf16* __restrict__ Wt2,
                                                const float* __restrict__ bout,
                                                float* __restrict__ Out) {
  int m0 = blockIdx.x * 64, n0 = blockIdx.y * 64;
  int wave = threadIdx.x >> 6, lane = threadIdx.x & 63;
  int l16 = lane & 15, quad = lane >> 4;

  f32x4 acc[4] = {};
  const bf16* Arow = AO + (size_t)(m0 + wave * 16 + l16) * 512;
  gemm_acc_16x64(Arow, Wt2, n0, 512, l16, quad, acc);

#pragma unroll
  for (int ct = 0; ct < 4; ct++) {
    int c = n0 + ct * 16 + l16;
    float bias = bout[c];
#pragma unroll
    for (int r = 0; r < 4; r++) {
      int m = m0 + wave * 16 + quad * 4 + r;
      Out[(size_t)m * 512 + c] = acc[ct][r] + bias;
    }
  }
}

// ---------------------------------------------------------------------------
// ws (44 MB used): Q 0 | K 8388608 | Vt 16777216 (tiled) | AObf 25165824 |
//                  Wt1 33554432 | Wt2 35127296 | Xb 35651584 .. 44040192
// ---------------------------------------------------------------------------
extern "C" void kernel_launch(void* const* d_in, const int* in_sizes, int n_in,
                              void* d_out, int out_size, void* d_ws,
                              size_t ws_size, hipStream_t stream) {
  const float* x = (const float*)d_in[0];
  const float* w_qkv = (const float*)d_in[1];
  const float* b_qkv = (const float*)d_in[2];
  const float* w_out = (const float*)d_in[3];
  const float* b_out = (const float*)d_in[4];
  float* out = (float*)d_out;

  char* ws = (char*)d_ws;
  bf16* Q = (bf16*)(ws + 0);
  bf16* K = (bf16*)(ws + 8388608);
  bf16* Vt = (bf16*)(ws + 16777216);
  bf16* AObf = (bf16*)(ws + 25165824);
  bf16* Wt1 = (bf16*)(ws + 33554432);
  bf16* Wt2 = (bf16*)(ws + 35127296);
  bf16* Xb = (bf16*)(ws + 35651584);

  cvt_x<<<4096, 256, 0, stream>>>(x, Xb);
  transpose64<<<dim3(8, 24), 256, 0, stream>>>(w_qkv, Wt1, 512, 1536);
  transpose64<<<dim3(8, 8), 256, 0, stream>>>(w_out, Wt2, 512, 512);
  qkv_gemm<<<dim3(128, 24), 256, 0, stream>>>(Xb, Wt1, b_qkv, Q, K, Vt);
  flash_attn<<<dim3(64, 16), 256, 0, stream>>>(Q, K, Vt, AObf);
  out_gemm<<<dim3(128, 8), 256, 0, stream>>>(AObf, Wt2, b_out, out);
}

// Round 16
// 257.658 us; speedup vs baseline: 2.6645x; 1.4160x over previous
//
#include <hip/hip_runtime.h>

typedef __bf16 bf16;
typedef __bf16 bf16x8 __attribute__((ext_vector_type(8)));
typedef float f32x4 __attribute__((ext_vector_type(4)));
typedef float f32x4n __attribute__((ext_vector_type(4)));

#define MFMA16(a, b, c) __builtin_amdgcn_mfma_f32_16x16x32_bf16((a), (b), (c), 0, 0, 0)

static __device__ __forceinline__ bf16x8 ldg8(const bf16* p) {
  return *(const bf16x8*)p;
}

// ===========================================================================
// Established: 5 fp32 inputs, FP32 output, ws >= 61.4MB. r15 PASS 365us:
// flash 155us after coalesced staging + XOR-swizzled LDS (fragmentation
// theory confirmed, 3.1x). Remaining ~210us = GEMMs with the same fragmented
// ldg8 pattern. This round: pack ALL GEMM operands into 8KB-contiguous
// 64x64 (row,k) tiles; GEMMs stage A+B tiles coalesced into swizzled LDS.
// Packed layouts: T[tile][kchunk][64 row][64 k], tile-block = 8KB contig.
// ===========================================================================

// ---------------------------------------------------------------------------
// cvt_pack_x: x fp32 [8192][512] -> Xp packed bf16. Grid (128 mtile, 8 kc).
// ---------------------------------------------------------------------------
__global__ __launch_bounds__(256) void cvt_pack_x(const float* __restrict__ x,
                                                  bf16* __restrict__ Xp) {
  int mt = blockIdx.x, kc = blockIdx.y;
  int row = threadIdx.x >> 4;          // 0..15 (x4 rounds)
  int c4 = (threadIdx.x & 15) * 4;     // k offset 0..60
  bf16* tile = Xp + ((size_t)mt * 8 + kc) * 4096;
#pragma unroll
  for (int i = 0; i < 4; i++) {
    int r = i * 16 + row;
    const float* src = x + (size_t)(mt * 64 + r) * 512 + kc * 64 + c4;
    float4 v = *(const float4*)src;
    bf16* d = tile + r * 64 + c4;
    d[0] = (bf16)v.x; d[1] = (bf16)v.y; d[2] = (bf16)v.z; d[3] = (bf16)v.w;
  }
}

// ---------------------------------------------------------------------------
// transpose_pack_w: W fp32 [K][N] -> Wp packed [ntile][kchunk][64n][64k].
// Grid (K/64 kchunk, N/64 ntile).
// ---------------------------------------------------------------------------
__global__ __launch_bounds__(256) void transpose_pack_w(const float* __restrict__ W,
                                                        bf16* __restrict__ Wp,
                                                        int N, int KC) {
  __shared__ bf16 tile[64][65];  // [k][n]
  int kc = blockIdx.x, nt = blockIdx.y;
  int c = threadIdx.x & 63;
  int r4 = threadIdx.x >> 6;
#pragma unroll
  for (int i = 0; i < 16; i++) {
    int r = r4 * 16 + i;  // k row
    tile[r][c] = (bf16)W[(size_t)(kc * 64 + r) * N + nt * 64 + c];
  }
  __syncthreads();
  bf16* dst = Wp + ((size_t)nt * KC + kc) * 4096;
#pragma unroll
  for (int i = 0; i < 16; i++) {
    int r = r4 * 16 + i;  // n row
    dst[r * 64 + c] = tile[c][r];  // contiguous in k
  }
}

// ---------------------------------------------------------------------------
// Packed-tile GEMM core: block (64m x 64n), 4 waves, K-chunks of 64.
// Stage A (8KB) + B (8KB) coalesced into XOR-swizzled LDS; frags via
// ds_read_b128. acc[ct][r] = C[quad*4+r][ct*16+l16] (MFMA C-layout).
// ---------------------------------------------------------------------------
__device__ __forceinline__ void gemm_core_packed(const bf16* __restrict__ Ap,
                                                 const bf16* __restrict__ Bp,
                                                 int KC, bf16* Atile, bf16* Btile,
                                                 int tid, int wave, int l16,
                                                 int quad, f32x4 acc[4]) {
  for (int kc = 0; kc < KC; kc++) {
    __syncthreads();  // previous chunk's reads complete
    const bf16* ag = Ap + (size_t)kc * 4096;
    const bf16* bg = Bp + (size_t)kc * 4096;
#pragma unroll
    for (int rnd = 0; rnd < 2; rnd++) {
      int e = (rnd * 256 + tid) * 8;
      int row = e >> 6;
      int c16 = (e & 63) >> 3;
      int unit = row * 8 + (c16 ^ (row & 7));
      *(bf16x8*)&Atile[unit * 8] = ldg8(ag + e);
      *(bf16x8*)&Btile[unit * 8] = ldg8(bg + e);
    }
    __syncthreads();

    int ar = wave * 16 + l16;
    bf16x8 a0 = *(const bf16x8*)&Atile[(ar * 8 + (quad ^ (ar & 7))) * 8];
    bf16x8 a1 = *(const bf16x8*)&Atile[(ar * 8 + ((4 + quad) ^ (ar & 7))) * 8];
#pragma unroll
    for (int ct = 0; ct < 4; ct++) {
      int n = ct * 16 + l16;
      bf16x8 b0 = *(const bf16x8*)&Btile[(n * 8 + (quad ^ (n & 7))) * 8];
      bf16x8 b1 = *(const bf16x8*)&Btile[(n * 8 + ((4 + quad) ^ (n & 7))) * 8];
      acc[ct] = MFMA16(a0, b0, acc[ct]);
      acc[ct] = MFMA16(a1, b1, acc[ct]);
    }
  }
}

// ---------------------------------------------------------------------------
// QKV projection v2: Xp @ Wp1 -> Q,K:[bh][n][d]; V tiled [bh][nt][d][64].
// Grid (128 mtile, 24 ntile).
// ---------------------------------------------------------------------------
__global__ __launch_bounds__(256) void qkv_gemm(const bf16* __restrict__ Xp,
                                                const bf16* __restrict__ Wp1,
                                                const float* __restrict__ bqkv,
                                                bf16* __restrict__ Q,
                                                bf16* __restrict__ Kh,
                                                bf16* __restrict__ Vt) {
  int mt = blockIdx.x, nt = blockIdx.y;
  int tid = threadIdx.x;
  int wave = tid >> 6, lane = tid & 63;
  int l16 = lane & 15, quad = lane >> 4;

  __shared__ __align__(16) bf16 Atile[4096];
  __shared__ __align__(16) bf16 Btile[4096];

  f32x4 acc[4] = {};
  gemm_core_packed(Xp + (size_t)mt * 8 * 4096, Wp1 + (size_t)nt * 8 * 4096, 8,
                   Atile, Btile, tid, wave, l16, quad, acc);

#pragma unroll
  for (int ct = 0; ct < 4; ct++) {
    int c = nt * 64 + ct * 16 + l16;
    float bias = bqkv[c];
    int which = c >> 9, inner = c & 511;
    int h = inner >> 6, d = inner & 63;
#pragma unroll
    for (int r = 0; r < 4; r++) {
      int m = mt * 64 + wave * 16 + quad * 4 + r;
      int b = m >> 12, n = m & 4095;
      int bh = b * 8 + h;
      bf16 v = (bf16)(acc[ct][r] + bias);
      if (which == 0)
        Q[((size_t)bh * 4096 + n) * 64 + d] = v;
      else if (which == 1)
        Kh[((size_t)bh * 4096 + n) * 64 + d] = v;
      else
        Vt[(((size_t)bh * 64 + (n >> 6)) * 64 + d) * 64 + (n & 63)] = v;
    }
  }
}

// ---------------------------------------------------------------------------
// Flash attention (r15-proven core). Epilogue writes PACKED Ap for out_gemm:
// Ap[mtile=b*64+qt][kchunk=h][m=wave*16+quad*4+r][k=ct*16+l16].
// ---------------------------------------------------------------------------
__global__ __launch_bounds__(256) void flash_attn(const bf16* __restrict__ Q,
                                                  const bf16* __restrict__ K,
                                                  const bf16* __restrict__ Vt,
                                                  bf16* __restrict__ Ap) {
  int qt = blockIdx.x, bh = blockIdx.y;
  int tid = threadIdx.x;
  int wave = tid >> 6, lane = tid & 63;
  int l16 = lane & 15, quad = lane >> 4;

  const bf16* Qh = Q + (size_t)bh * 4096 * 64;
  const bf16* Kh = K + (size_t)bh * 4096 * 64;
  const bf16* Vh = Vt + (size_t)bh * 64 * 4096;

  __shared__ __align__(16) bf16 Klds[4096];
  __shared__ __align__(16) bf16 Vlds[4096];
  __shared__ __align__(16) bf16 P[4][16][72];

  int qrow = qt * 64 + wave * 16;
  bf16x8 aq0 = ldg8(Qh + (size_t)(qrow + l16) * 64 + quad * 8);
  bf16x8 aq1 = ldg8(Qh + (size_t)(qrow + l16) * 64 + 32 + quad * 8);

  f32x4 o[4] = {};
  float l_lane[4] = {0.f, 0.f, 0.f, 0.f};

  for (int kb = 0; kb < 4096; kb += 64) {
    __syncthreads();
    const bf16* kg = Kh + (size_t)kb * 64;
    const bf16* vg = Vh + (size_t)kb * 64;
#pragma unroll
    for (int rnd = 0; rnd < 2; rnd++) {
      int e = (rnd * 256 + tid) * 8;
      int row = e >> 6;
      int c16 = (e & 63) >> 3;
      int unit = row * 8 + (c16 ^ (row & 7));
      *(bf16x8*)&Klds[unit * 8] = ldg8(kg + e);
      *(bf16x8*)&Vlds[unit * 8] = ldg8(vg + e);
    }
    __syncthreads();

    f32x4 s[4] = {};
#pragma unroll
    for (int ct = 0; ct < 4; ct++) {
      int n = ct * 16 + l16;
      bf16x8 b0 = *(const bf16x8*)&Klds[(n * 8 + (quad ^ (n & 7))) * 8];
      bf16x8 b1 = *(const bf16x8*)&Klds[(n * 8 + ((4 + quad) ^ (n & 7))) * 8];
      s[ct] = MFMA16(aq0, b0, s[ct]);
      s[ct] = MFMA16(aq1, b1, s[ct]);
    }
#pragma unroll
    for (int ct = 0; ct < 4; ct++) {
#pragma unroll
      for (int r = 0; r < 4; r++) {
        float p = __expf(s[ct][r] * 0.125f);
        l_lane[r] += p;
        P[wave][quad * 4 + r][ct * 16 + l16] = (bf16)p;
      }
    }
    bf16x8 ap0 = ldg8(&P[wave][l16][quad * 8]);
    bf16x8 ap1 = ldg8(&P[wave][l16][32 + quad * 8]);
#pragma unroll
    for (int ct = 0; ct < 4; ct++) {
      int d = ct * 16 + l16;
      bf16x8 bv0 = *(const bf16x8*)&Vlds[(d * 8 + (quad ^ (d & 7))) * 8];
      bf16x8 bv1 = *(const bf16x8*)&Vlds[(d * 8 + ((4 + quad) ^ (d & 7))) * 8];
      o[ct] = MFMA16(ap0, bv0, o[ct]);
      o[ct] = MFMA16(ap1, bv1, o[ct]);
    }
  }

  float inv[4];
#pragma unroll
  for (int r = 0; r < 4; r++) {
    float l = l_lane[r];
#pragma unroll
    for (int off = 1; off < 16; off <<= 1) l += __shfl_xor(l, off);
    inv[r] = 1.0f / l;
  }

  int b = bh >> 3, h = bh & 7;
  int mtile = b * 64 + qt;
  bf16* apt = Ap + ((size_t)mtile * 8 + h) * 4096;
#pragma unroll
  for (int r = 0; r < 4; r++) {
    int m = wave * 16 + quad * 4 + r;
#pragma unroll
    for (int ct = 0; ct < 4; ct++) {
      apt[m * 64 + ct * 16 + l16] = (bf16)(o[ct][r] * inv[r]);
    }
  }
}

// ---------------------------------------------------------------------------
// Output projection v2: Ap(packed) @ Wp2 -> FP32 out. Grid (128, 8).
// ---------------------------------------------------------------------------
__global__ __launch_bounds__(256) void out_gemm(const bf16* __restrict__ Ap,
                                                const bf16* __restrict__ Wp2,
                                                const float* __restrict__ bout,
                                                float* __restrict__ Out) {
  int mt = blockIdx.x, nt = blockIdx.y;
  int tid = threadIdx.x;
  int wave = tid >> 6, lane = tid & 63;
  int l16 = lane & 15, quad = lane >> 4;

  __shared__ __align__(16) bf16 Atile[4096];
  __shared__ __align__(16) bf16 Btile[4096];

  f32x4 acc[4] = {};
  gemm_core_packed(Ap + (size_t)mt * 8 * 4096, Wp2 + (size_t)nt * 8 * 4096, 8,
                   Atile, Btile, tid, wave, l16, quad, acc);

#pragma unroll
  for (int ct = 0; ct < 4; ct++) {
    int c = nt * 64 + ct * 16 + l16;
    float bias = bout[c];
#pragma unroll
    for (int r = 0; r < 4; r++) {
      int m = mt * 64 + wave * 16 + quad * 4 + r;
      Out[(size_t)m * 512 + c] = acc[ct][r] + bias;
    }
  }
}

// ---------------------------------------------------------------------------
// ws (44 MB): Q 0 | K 8388608 | Vt 16777216 | Ap 25165824 | Wp1 33554432 |
//             Wp2 35127296 | Xp 35651584 .. 44040192
// ---------------------------------------------------------------------------
extern "C" void kernel_launch(void* const* d_in, const int* in_sizes, int n_in,
                              void* d_out, int out_size, void* d_ws,
                              size_t ws_size, hipStream_t stream) {
  const float* x = (const float*)d_in[0];
  const float* w_qkv = (const float*)d_in[1];
  const float* b_qkv = (const float*)d_in[2];
  const float* w_out = (const float*)d_in[3];
  const float* b_out = (const float*)d_in[4];
  float* out = (float*)d_out;

  char* ws = (char*)d_ws;
  bf16* Q = (bf16*)(ws + 0);
  bf16* K = (bf16*)(ws + 8388608);
  bf16* Vt = (bf16*)(ws + 16777216);
  bf16* Ap = (bf16*)(ws + 25165824);
  bf16* Wp1 = (bf16*)(ws + 33554432);
  bf16* Wp2 = (bf16*)(ws + 35127296);
  bf16* Xp = (bf16*)(ws + 35651584);

  cvt_pack_x<<<dim3(128, 8), 256, 0, stream>>>(x, Xp);
  transpose_pack_w<<<dim3(8, 24), 256, 0, stream>>>(w_qkv, Wp1, 1536, 8);
  transpose_pack_w<<<dim3(8, 8), 256, 0, stream>>>(w_out, Wp2, 512, 8);
  qkv_gemm<<<dim3(128, 24), 256, 0, stream>>>(Xp, Wp1, b_qkv, Q, K, Vt);
  flash_attn<<<dim3(64, 16), 256, 0, stream>>>(Q, K, Vt, Ap);
  out_gemm<<<dim3(128, 8), 256, 0, stream>>>(Ap, Wp2, b_out, out);
}

// Round 17
// 246.104 us; speedup vs baseline: 2.7896x; 1.0469x over previous
//
#include <hip/hip_runtime.h>

typedef __bf16 bf16;
typedef __bf16 bf16x8 __attribute__((ext_vector_type(8)));
typedef float f32x4 __attribute__((ext_vector_type(4)));

#define MFMA16(a, b, c) __builtin_amdgcn_mfma_f32_16x16x32_bf16((a), (b), (c), 0, 0, 0)

static __device__ __forceinline__ bf16x8 ldg8(const bf16* p) {
  return *(const bf16x8*)p;
}

// ===========================================================================
// Established: 5 fp32 inputs, FP32 output, ws >= 61.4MB. r15: coalesced+
// swizzled LDS staging fixed VMEM fragmentation (flash 479->155). r16: packed
// GEMMs fixed the rest (total 365->258); flash now 60% of runtime and
// stall-bound (5.8k cyc/tile vs 2.2k pipe need): single-buffered staging puts
// L2 latency on the per-tile critical path. This round: register-prefetch
// pipeline (issue tile k+1's global loads into VGPRs during tile k's compute)
// + fold softmax /8 into Q at qkv epilogue (exact bf16 pow2 scale).
// ===========================================================================

__global__ __launch_bounds__(256) void cvt_pack_x(const float* __restrict__ x,
                                                  bf16* __restrict__ Xp) {
  int mt = blockIdx.x, kc = blockIdx.y;
  int row = threadIdx.x >> 4;
  int c4 = (threadIdx.x & 15) * 4;
  bf16* tile = Xp + ((size_t)mt * 8 + kc) * 4096;
#pragma unroll
  for (int i = 0; i < 4; i++) {
    int r = i * 16 + row;
    const float* src = x + (size_t)(mt * 64 + r) * 512 + kc * 64 + c4;
    float4 v = *(const float4*)src;
    bf16* d = tile + r * 64 + c4;
    d[0] = (bf16)v.x; d[1] = (bf16)v.y; d[2] = (bf16)v.z; d[3] = (bf16)v.w;
  }
}

__global__ __launch_bounds__(256) void transpose_pack_w(const float* __restrict__ W,
                                                        bf16* __restrict__ Wp,
                                                        int N, int KC) {
  __shared__ bf16 tile[64][65];
  int kc = blockIdx.x, nt = blockIdx.y;
  int c = threadIdx.x & 63;
  int r4 = threadIdx.x >> 6;
#pragma unroll
  for (int i = 0; i < 16; i++) {
    int r = r4 * 16 + i;
    tile[r][c] = (bf16)W[(size_t)(kc * 64 + r) * N + nt * 64 + c];
  }
  __syncthreads();
  bf16* dst = Wp + ((size_t)nt * KC + kc) * 4096;
#pragma unroll
  for (int i = 0; i < 16; i++) {
    int r = r4 * 16 + i;
    dst[r * 64 + c] = tile[c][r];
  }
}

// ---------------------------------------------------------------------------
// Packed-tile GEMM core (r16-proven).
// ---------------------------------------------------------------------------
__device__ __forceinline__ void gemm_core_packed(const bf16* __restrict__ Ap,
                                                 const bf16* __restrict__ Bp,
                                                 int KC, bf16* Atile, bf16* Btile,
                                                 int tid, int wave, int l16,
                                                 int quad, f32x4 acc[4]) {
  for (int kc = 0; kc < KC; kc++) {
    __syncthreads();
    const bf16* ag = Ap + (size_t)kc * 4096;
    const bf16* bg = Bp + (size_t)kc * 4096;
#pragma unroll
    for (int rnd = 0; rnd < 2; rnd++) {
      int e = (rnd * 256 + tid) * 8;
      int row = e >> 6;
      int c16 = (e & 63) >> 3;
      int unit = row * 8 + (c16 ^ (row & 7));
      *(bf16x8*)&Atile[unit * 8] = ldg8(ag + e);
      *(bf16x8*)&Btile[unit * 8] = ldg8(bg + e);
    }
    __syncthreads();

    int ar = wave * 16 + l16;
    bf16x8 a0 = *(const bf16x8*)&Atile[(ar * 8 + (quad ^ (ar & 7))) * 8];
    bf16x8 a1 = *(const bf16x8*)&Atile[(ar * 8 + ((4 + quad) ^ (ar & 7))) * 8];
#pragma unroll
    for (int ct = 0; ct < 4; ct++) {
      int n = ct * 16 + l16;
      bf16x8 b0 = *(const bf16x8*)&Btile[(n * 8 + (quad ^ (n & 7))) * 8];
      bf16x8 b1 = *(const bf16x8*)&Btile[(n * 8 + ((4 + quad) ^ (n & 7))) * 8];
      acc[ct] = MFMA16(a0, b0, acc[ct]);
      acc[ct] = MFMA16(a1, b1, acc[ct]);
    }
  }
}

// ---------------------------------------------------------------------------
// QKV projection. Q is PRE-SCALED by 0.125 (exact pow2 in bf16) so flash's
// softmax needs no per-element scale mul. Q,K:[bh][n][d]; V tiled.
// ---------------------------------------------------------------------------
__global__ __launch_bounds__(256) void qkv_gemm(const bf16* __restrict__ Xp,
                                                const bf16* __restrict__ Wp1,
                                                const float* __restrict__ bqkv,
                                                bf16* __restrict__ Q,
                                                bf16* __restrict__ Kh,
                                                bf16* __restrict__ Vt) {
  int mt = blockIdx.x, nt = blockIdx.y;
  int tid = threadIdx.x;
  int wave = tid >> 6, lane = tid & 63;
  int l16 = lane & 15, quad = lane >> 4;

  __shared__ __align__(16) bf16 Atile[4096];
  __shared__ __align__(16) bf16 Btile[4096];

  f32x4 acc[4] = {};
  gemm_core_packed(Xp + (size_t)mt * 8 * 4096, Wp1 + (size_t)nt * 8 * 4096, 8,
                   Atile, Btile, tid, wave, l16, quad, acc);

#pragma unroll
  for (int ct = 0; ct < 4; ct++) {
    int c = nt * 64 + ct * 16 + l16;
    float bias = bqkv[c];
    int which = c >> 9, inner = c & 511;
    int h = inner >> 6, d = inner & 63;
#pragma unroll
    for (int r = 0; r < 4; r++) {
      int m = mt * 64 + wave * 16 + quad * 4 + r;
      int b = m >> 12, n = m & 4095;
      int bh = b * 8 + h;
      float v = acc[ct][r] + bias;
      if (which == 0)
        Q[((size_t)bh * 4096 + n) * 64 + d] = (bf16)(v * 0.125f);
      else if (which == 1)
        Kh[((size_t)bh * 4096 + n) * 64 + d] = (bf16)v;
      else
        Vt[(((size_t)bh * 64 + (n >> 6)) * 64 + d) * 64 + (n & 63)] = (bf16)v;
    }
  }
}

// ---------------------------------------------------------------------------
// Flash attention v5: r15 core + register-prefetch pipeline.
// Per tile: ds_write(prefetched regs) -> barrier -> ISSUE next tile's global
// loads (non-blocking; vmcnt waits land at next iteration's ds_write) ->
// compute (QK MFMA, exp, P round-trip, PV MFMA) -> loop.
// ---------------------------------------------------------------------------
__global__ __launch_bounds__(256) void flash_attn(const bf16* __restrict__ Q,
                                                  const bf16* __restrict__ K,
                                                  const bf16* __restrict__ Vt,
                                                  bf16* __restrict__ Ap) {
  int qt = blockIdx.x, bh = blockIdx.y;
  int tid = threadIdx.x;
  int wave = tid >> 6, lane = tid & 63;
  int l16 = lane & 15, quad = lane >> 4;

  const bf16* Qh = Q + (size_t)bh * 4096 * 64;
  const bf16* Kh = K + (size_t)bh * 4096 * 64;
  const bf16* Vh = Vt + (size_t)bh * 64 * 4096;

  __shared__ __align__(16) bf16 Klds[4096];
  __shared__ __align__(16) bf16 Vlds[4096];
  __shared__ __align__(16) bf16 P[4][16][72];

  int qrow = qt * 64 + wave * 16;
  bf16x8 aq0 = ldg8(Qh + (size_t)(qrow + l16) * 64 + quad * 8);
  bf16x8 aq1 = ldg8(Qh + (size_t)(qrow + l16) * 64 + 32 + quad * 8);

  f32x4 o[4] = {};
  float l_lane[4] = {0.f, 0.f, 0.f, 0.f};

  // staging geometry (loop-invariant)
  int e0 = tid * 8, e1 = (256 + tid) * 8;
  int r0 = e0 >> 6, r1 = e1 >> 6;
  int u0 = r0 * 8 + (((e0 & 63) >> 3) ^ (r0 & 7));
  int u1 = r1 * 8 + (((e1 & 63) >> 3) ^ (r1 & 7));

  // prologue: prefetch tile 0
  bf16x8 kp0 = ldg8(Kh + e0), kp1 = ldg8(Kh + e1);
  bf16x8 vp0 = ldg8(Vh + e0), vp1 = ldg8(Vh + e1);

  for (int kb = 0; kb < 4096; kb += 64) {
    __syncthreads();  // prior tile's LDS reads complete
    *(bf16x8*)&Klds[u0 * 8] = kp0;
    *(bf16x8*)&Klds[u1 * 8] = kp1;
    *(bf16x8*)&Vlds[u0 * 8] = vp0;
    *(bf16x8*)&Vlds[u1 * 8] = vp1;
    __syncthreads();

    // issue next tile's loads now; they fly during this tile's compute
    if (kb + 64 < 4096) {
      const bf16* kg = Kh + (size_t)(kb + 64) * 64;
      const bf16* vg = Vh + (size_t)(kb + 64) * 64;
      kp0 = ldg8(kg + e0);
      kp1 = ldg8(kg + e1);
      vp0 = ldg8(vg + e0);
      vp1 = ldg8(vg + e1);
    }

    // ---- S = Q K^T (Q pre-scaled by 1/8) ----
    f32x4 s[4] = {};
#pragma unroll
    for (int ct = 0; ct < 4; ct++) {
      int n = ct * 16 + l16;
      bf16x8 b0 = *(const bf16x8*)&Klds[(n * 8 + (quad ^ (n & 7))) * 8];
      bf16x8 b1 = *(const bf16x8*)&Klds[(n * 8 + ((4 + quad) ^ (n & 7))) * 8];
      s[ct] = MFMA16(aq0, b0, s[ct]);
      s[ct] = MFMA16(aq1, b1, s[ct]);
    }
    // ---- p = exp(s); accumulate l; stage P (per-wave C-layout) ----
#pragma unroll
    for (int ct = 0; ct < 4; ct++) {
#pragma unroll
      for (int r = 0; r < 4; r++) {
        float p = __expf(s[ct][r]);
        l_lane[r] += p;
        P[wave][quad * 4 + r][ct * 16 + l16] = (bf16)p;
      }
    }
    // ---- O += P V ----
    bf16x8 ap0 = ldg8(&P[wave][l16][quad * 8]);
    bf16x8 ap1 = ldg8(&P[wave][l16][32 + quad * 8]);
#pragma unroll
    for (int ct = 0; ct < 4; ct++) {
      int d = ct * 16 + l16;
      bf16x8 bv0 = *(const bf16x8*)&Vlds[(d * 8 + (quad ^ (d & 7))) * 8];
      bf16x8 bv1 = *(const bf16x8*)&Vlds[(d * 8 + ((4 + quad) ^ (d & 7))) * 8];
      o[ct] = MFMA16(ap0, bv0, o[ct]);
      o[ct] = MFMA16(ap1, bv1, o[ct]);
    }
  }

  float inv[4];
#pragma unroll
  for (int r = 0; r < 4; r++) {
    float l = l_lane[r];
#pragma unroll
    for (int off = 1; off < 16; off <<= 1) l += __shfl_xor(l, off);
    inv[r] = 1.0f / l;
  }

  int b = bh >> 3, h = bh & 7;
  int mtile = b * 64 + qt;
  bf16* apt = Ap + ((size_t)mtile * 8 + h) * 4096;
#pragma unroll
  for (int r = 0; r < 4; r++) {
    int m = wave * 16 + quad * 4 + r;
#pragma unroll
    for (int ct = 0; ct < 4; ct++) {
      apt[m * 64 + ct * 16 + l16] = (bf16)(o[ct][r] * inv[r]);
    }
  }
}

// ---------------------------------------------------------------------------
// Output projection: Ap(packed) @ Wp2 -> FP32 out.
// ---------------------------------------------------------------------------
__global__ __launch_bounds__(256) void out_gemm(const bf16* __restrict__ Ap,
                                                const bf16* __restrict__ Wp2,
                                                const float* __restrict__ bout,
                                                float* __restrict__ Out) {
  int mt = blockIdx.x, nt = blockIdx.y;
  int tid = threadIdx.x;
  int wave = tid >> 6, lane = tid & 63;
  int l16 = lane & 15, quad = lane >> 4;

  __shared__ __align__(16) bf16 Atile[4096];
  __shared__ __align__(16) bf16 Btile[4096];

  f32x4 acc[4] = {};
  gemm_core_packed(Ap + (size_t)mt * 8 * 4096, Wp2 + (size_t)nt * 8 * 4096, 8,
                   Atile, Btile, tid, wave, l16, quad, acc);

#pragma unroll
  for (int ct = 0; ct < 4; ct++) {
    int c = nt * 64 + ct * 16 + l16;
    float bias = bout[c];
#pragma unroll
    for (int r = 0; r < 4; r++) {
      int m = mt * 64 + wave * 16 + quad * 4 + r;
      Out[(size_t)m * 512 + c] = acc[ct][r] + bias;
    }
  }
}

// ---------------------------------------------------------------------------
// ws (44 MB): Q 0 | K 8388608 | Vt 16777216 | Ap 25165824 | Wp1 33554432 |
//             Wp2 35127296 | Xp 35651584 .. 44040192
// ---------------------------------------------------------------------------
extern "C" void kernel_launch(void* const* d_in, const int* in_sizes, int n_in,
                              void* d_out, int out_size, void* d_ws,
                              size_t ws_size, hipStream_t stream) {
  const float* x = (const float*)d_in[0];
  const float* w_qkv = (const float*)d_in[1];
  const float* b_qkv = (const float*)d_in[2];
  const float* w_out = (const float*)d_in[3];
  const float* b_out = (const float*)d_in[4];
  float* out = (float*)d_out;

  char* ws = (char*)d_ws;
  bf16* Q = (bf16*)(ws + 0);
  bf16* K = (bf16*)(ws + 8388608);
  bf16* Vt = (bf16*)(ws + 16777216);
  bf16* Ap = (bf16*)(ws + 25165824);
  bf16* Wp1 = (bf16*)(ws + 33554432);
  bf16* Wp2 = (bf16*)(ws + 35127296);
  bf16* Xp = (bf16*)(ws + 35651584);

  cvt_pack_x<<<dim3(128, 8), 256, 0, stream>>>(x, Xp);
  transpose_pack_w<<<dim3(8, 24), 256, 0, stream>>>(w_qkv, Wp1, 1536, 8);
  transpose_pack_w<<<dim3(8, 8), 256, 0, stream>>>(w_out, Wp2, 512, 8);
  qkv_gemm<<<dim3(128, 24), 256, 0, stream>>>(Xp, Wp1, b_qkv, Q, K, Vt);
  flash_attn<<<dim3(64, 16), 256, 0, stream>>>(Q, K, Vt, Ap);
  out_gemm<<<dim3(128, 8), 256, 0, stream>>>(Ap, Wp2, b_out, out);
}

// Round 18
// 244.506 us; speedup vs baseline: 2.8078x; 1.0065x over previous
//
#include <hip/hip_runtime.h>

typedef __bf16 bf16;
typedef __bf16 bf16x8 __attribute__((ext_vector_type(8)));
typedef float f32x4 __attribute__((ext_vector_type(4)));

#define MFMA16(a, b, c) __builtin_amdgcn_mfma_f32_16x16x32_bf16((a), (b), (c), 0, 0, 0)

static __device__ __forceinline__ bf16x8 ldg8(const bf16* p) {
  return *(const bf16x8*)p;
}

// ===========================================================================
// Established: 5 fp32 inputs, FP32 output, ws >= 61.4MB. Ladder: 803 (r10)
// -> 675 (no-barrier/const-max softmax) -> 365 (coalesced+swizzled staging)
// -> 258 (packed GEMMs) -> 246 (reg-prefetch). flash 141us: in-tile serial
// chain QK->exp->Pwrite->lgkm->Pread->PV dominates. This round: defer PV one
// tile (double-buffered Vlds; P single buffer — PV's read of P_{k-1} precedes
// the P_k write in per-wave DS program order). LDS 33.2KB -> 4 blocks/CU kept.
// ===========================================================================

__global__ __launch_bounds__(256) void cvt_pack_x(const float* __restrict__ x,
                                                  bf16* __restrict__ Xp) {
  int mt = blockIdx.x, kc = blockIdx.y;
  int row = threadIdx.x >> 4;
  int c4 = (threadIdx.x & 15) * 4;
  bf16* tile = Xp + ((size_t)mt * 8 + kc) * 4096;
#pragma unroll
  for (int i = 0; i < 4; i++) {
    int r = i * 16 + row;
    const float* src = x + (size_t)(mt * 64 + r) * 512 + kc * 64 + c4;
    float4 v = *(const float4*)src;
    bf16* d = tile + r * 64 + c4;
    d[0] = (bf16)v.x; d[1] = (bf16)v.y; d[2] = (bf16)v.z; d[3] = (bf16)v.w;
  }
}

__global__ __launch_bounds__(256) void transpose_pack_w(const float* __restrict__ W,
                                                        bf16* __restrict__ Wp,
                                                        int N, int KC) {
  __shared__ bf16 tile[64][65];
  int kc = blockIdx.x, nt = blockIdx.y;
  int c = threadIdx.x & 63;
  int r4 = threadIdx.x >> 6;
#pragma unroll
  for (int i = 0; i < 16; i++) {
    int r = r4 * 16 + i;
    tile[r][c] = (bf16)W[(size_t)(kc * 64 + r) * N + nt * 64 + c];
  }
  __syncthreads();
  bf16* dst = Wp + ((size_t)nt * KC + kc) * 4096;
#pragma unroll
  for (int i = 0; i < 16; i++) {
    int r = r4 * 16 + i;
    dst[r * 64 + c] = tile[c][r];
  }
}

// ---------------------------------------------------------------------------
// Packed-tile GEMM core (r16-proven).
// ---------------------------------------------------------------------------
__device__ __forceinline__ void gemm_core_packed(const bf16* __restrict__ Ap,
                                                 const bf16* __restrict__ Bp,
                                                 int KC, bf16* Atile, bf16* Btile,
                                                 int tid, int wave, int l16,
                                                 int quad, f32x4 acc[4]) {
  for (int kc = 0; kc < KC; kc++) {
    __syncthreads();
    const bf16* ag = Ap + (size_t)kc * 4096;
    const bf16* bg = Bp + (size_t)kc * 4096;
#pragma unroll
    for (int rnd = 0; rnd < 2; rnd++) {
      int e = (rnd * 256 + tid) * 8;
      int row = e >> 6;
      int c16 = (e & 63) >> 3;
      int unit = row * 8 + (c16 ^ (row & 7));
      *(bf16x8*)&Atile[unit * 8] = ldg8(ag + e);
      *(bf16x8*)&Btile[unit * 8] = ldg8(bg + e);
    }
    __syncthreads();

    int ar = wave * 16 + l16;
    bf16x8 a0 = *(const bf16x8*)&Atile[(ar * 8 + (quad ^ (ar & 7))) * 8];
    bf16x8 a1 = *(const bf16x8*)&Atile[(ar * 8 + ((4 + quad) ^ (ar & 7))) * 8];
#pragma unroll
    for (int ct = 0; ct < 4; ct++) {
      int n = ct * 16 + l16;
      bf16x8 b0 = *(const bf16x8*)&Btile[(n * 8 + (quad ^ (n & 7))) * 8];
      bf16x8 b1 = *(const bf16x8*)&Btile[(n * 8 + ((4 + quad) ^ (n & 7))) * 8];
      acc[ct] = MFMA16(a0, b0, acc[ct]);
      acc[ct] = MFMA16(a1, b1, acc[ct]);
    }
  }
}

// ---------------------------------------------------------------------------
// QKV projection. Q pre-scaled by 0.125 (exact pow2). Q,K:[bh][n][d]; V tiled.
// ---------------------------------------------------------------------------
__global__ __launch_bounds__(256) void qkv_gemm(const bf16* __restrict__ Xp,
                                                const bf16* __restrict__ Wp1,
                                                const float* __restrict__ bqkv,
                                                bf16* __restrict__ Q,
                                                bf16* __restrict__ Kh,
                                                bf16* __restrict__ Vt) {
  int mt = blockIdx.x, nt = blockIdx.y;
  int tid = threadIdx.x;
  int wave = tid >> 6, lane = tid & 63;
  int l16 = lane & 15, quad = lane >> 4;

  __shared__ __align__(16) bf16 Atile[4096];
  __shared__ __align__(16) bf16 Btile[4096];

  f32x4 acc[4] = {};
  gemm_core_packed(Xp + (size_t)mt * 8 * 4096, Wp1 + (size_t)nt * 8 * 4096, 8,
                   Atile, Btile, tid, wave, l16, quad, acc);

#pragma unroll
  for (int ct = 0; ct < 4; ct++) {
    int c = nt * 64 + ct * 16 + l16;
    float bias = bqkv[c];
    int which = c >> 9, inner = c & 511;
    int h = inner >> 6, d = inner & 63;
#pragma unroll
    for (int r = 0; r < 4; r++) {
      int m = mt * 64 + wave * 16 + quad * 4 + r;
      int b = m >> 12, n = m & 4095;
      int bh = b * 8 + h;
      float v = acc[ct][r] + bias;
      if (which == 0)
        Q[((size_t)bh * 4096 + n) * 64 + d] = (bf16)(v * 0.125f);
      else if (which == 1)
        Kh[((size_t)bh * 4096 + n) * 64 + d] = (bf16)v;
      else
        Vt[(((size_t)bh * 64 + (n >> 6)) * 64 + d) * 64 + (n & 63)] = (bf16)v;
    }
  }
}

// ---------------------------------------------------------------------------
// Flash attention v6: PV deferred one tile (software pipeline).
// Per tile k: stage K,V[k&1] -> barrier -> issue loads k+1 -> PV_{k-1}
// (P single buffer: read precedes this tile's write in wave program order;
// V from buffer (k-1)&1) + QK_k -> exp_k -> write P_k. Final PV after loop.
// ---------------------------------------------------------------------------
__global__ __launch_bounds__(256) void flash_attn(const bf16* __restrict__ Q,
                                                  const bf16* __restrict__ K,
                                                  const bf16* __restrict__ Vt,
                                                  bf16* __restrict__ Ap) {
  int qt = blockIdx.x, bh = blockIdx.y;
  int tid = threadIdx.x;
  int wave = tid >> 6, lane = tid & 63;
  int l16 = lane & 15, quad = lane >> 4;

  const bf16* Qh = Q + (size_t)bh * 4096 * 64;
  const bf16* Kh = K + (size_t)bh * 4096 * 64;
  const bf16* Vh = Vt + (size_t)bh * 64 * 4096;

  __shared__ __align__(16) bf16 Klds[4096];
  __shared__ __align__(16) bf16 Vlds[2][4096];
  __shared__ __align__(16) bf16 P[4][16][72];

  int qrow = qt * 64 + wave * 16;
  bf16x8 aq0 = ldg8(Qh + (size_t)(qrow + l16) * 64 + quad * 8);
  bf16x8 aq1 = ldg8(Qh + (size_t)(qrow + l16) * 64 + 32 + quad * 8);

  f32x4 o[4] = {};
  float l_lane[4] = {0.f, 0.f, 0.f, 0.f};

  // staging geometry (loop-invariant)
  int e0 = tid * 8, e1 = (256 + tid) * 8;
  int r0 = e0 >> 6, r1 = e1 >> 6;
  int u0 = r0 * 8 + (((e0 & 63) >> 3) ^ (r0 & 7));
  int u1 = r1 * 8 + (((e1 & 63) >> 3) ^ (r1 & 7));

  // prologue: prefetch tile 0
  bf16x8 kp0 = ldg8(Kh + e0), kp1 = ldg8(Kh + e1);
  bf16x8 vp0 = ldg8(Vh + e0), vp1 = ldg8(Vh + e1);

  for (int kb = 0; kb < 4096; kb += 64) {
    int buf = (kb >> 6) & 1;
    __syncthreads();  // prior tile's Klds/V[buf] reads complete
    *(bf16x8*)&Klds[u0 * 8] = kp0;
    *(bf16x8*)&Klds[u1 * 8] = kp1;
    *(bf16x8*)&Vlds[buf][u0 * 8] = vp0;
    *(bf16x8*)&Vlds[buf][u1 * 8] = vp1;
    __syncthreads();

    if (kb + 64 < 4096) {
      const bf16* kg = Kh + (size_t)(kb + 64) * 64;
      const bf16* vg = Vh + (size_t)(kb + 64) * 64;
      kp0 = ldg8(kg + e0);
      kp1 = ldg8(kg + e1);
      vp0 = ldg8(vg + e0);
      vp1 = ldg8(vg + e1);
    }

    // ---- PV for tile k-1 (P written a full tile ago; V from other buffer) ----
    if (kb > 0) {
      bf16x8 ap0 = ldg8(&P[wave][l16][quad * 8]);
      bf16x8 ap1 = ldg8(&P[wave][l16][32 + quad * 8]);
#pragma unroll
      for (int ct = 0; ct < 4; ct++) {
        int d = ct * 16 + l16;
        bf16x8 bv0 = *(const bf16x8*)&Vlds[buf ^ 1][(d * 8 + (quad ^ (d & 7))) * 8];
        bf16x8 bv1 =
            *(const bf16x8*)&Vlds[buf ^ 1][(d * 8 + ((4 + quad) ^ (d & 7))) * 8];
        o[ct] = MFMA16(ap0, bv0, o[ct]);
        o[ct] = MFMA16(ap1, bv1, o[ct]);
      }
    }

    // ---- S = Q K^T (Q pre-scaled by 1/8) ----
    f32x4 s[4] = {};
#pragma unroll
    for (int ct = 0; ct < 4; ct++) {
      int n = ct * 16 + l16;
      bf16x8 b0 = *(const bf16x8*)&Klds[(n * 8 + (quad ^ (n & 7))) * 8];
      bf16x8 b1 = *(const bf16x8*)&Klds[(n * 8 + ((4 + quad) ^ (n & 7))) * 8];
      s[ct] = MFMA16(aq0, b0, s[ct]);
      s[ct] = MFMA16(aq1, b1, s[ct]);
    }
    // ---- p = exp(s); accumulate l; write P_k (after PV's P reads) ----
#pragma unroll
    for (int ct = 0; ct < 4; ct++) {
#pragma unroll
      for (int r = 0; r < 4; r++) {
        float p = __expf(s[ct][r]);
        l_lane[r] += p;
        P[wave][quad * 4 + r][ct * 16 + l16] = (bf16)p;
      }
    }
  }

  // ---- final PV (tile 63: P just written, V in buffer 1) ----
  {
    bf16x8 ap0 = ldg8(&P[wave][l16][quad * 8]);
    bf16x8 ap1 = ldg8(&P[wave][l16][32 + quad * 8]);
#pragma unroll
    for (int ct = 0; ct < 4; ct++) {
      int d = ct * 16 + l16;
      bf16x8 bv0 = *(const bf16x8*)&Vlds[1][(d * 8 + (quad ^ (d & 7))) * 8];
      bf16x8 bv1 = *(const bf16x8*)&Vlds[1][(d * 8 + ((4 + quad) ^ (d & 7))) * 8];
      o[ct] = MFMA16(ap0, bv0, o[ct]);
      o[ct] = MFMA16(ap1, bv1, o[ct]);
    }
  }

  float inv[4];
#pragma unroll
  for (int r = 0; r < 4; r++) {
    float l = l_lane[r];
#pragma unroll
    for (int off = 1; off < 16; off <<= 1) l += __shfl_xor(l, off);
    inv[r] = 1.0f / l;
  }

  int b = bh >> 3, h = bh & 7;
  int mtile = b * 64 + qt;
  bf16* apt = Ap + ((size_t)mtile * 8 + h) * 4096;
#pragma unroll
  for (int r = 0; r < 4; r++) {
    int m = wave * 16 + quad * 4 + r;
#pragma unroll
    for (int ct = 0; ct < 4; ct++) {
      apt[m * 64 + ct * 16 + l16] = (bf16)(o[ct][r] * inv[r]);
    }
  }
}

// ---------------------------------------------------------------------------
// Output projection: Ap(packed) @ Wp2 -> FP32 out.
// ---------------------------------------------------------------------------
__global__ __launch_bounds__(256) void out_gemm(const bf16* __restrict__ Ap,
                                                const bf16* __restrict__ Wp2,
                                                const float* __restrict__ bout,
                                                float* __restrict__ Out) {
  int mt = blockIdx.x, nt = blockIdx.y;
  int tid = threadIdx.x;
  int wave = tid >> 6, lane = tid & 63;
  int l16 = lane & 15, quad = lane >> 4;

  __shared__ __align__(16) bf16 Atile[4096];
  __shared__ __align__(16) bf16 Btile[4096];

  f32x4 acc[4] = {};
  gemm_core_packed(Ap + (size_t)mt * 8 * 4096, Wp2 + (size_t)nt * 8 * 4096, 8,
                   Atile, Btile, tid, wave, l16, quad, acc);

#pragma unroll
  for (int ct = 0; ct < 4; ct++) {
    int c = nt * 64 + ct * 16 + l16;
    float bias = bout[c];
#pragma unroll
    for (int r = 0; r < 4; r++) {
      int m = mt * 64 + wave * 16 + quad * 4 + r;
      Out[(size_t)m * 512 + c] = acc[ct][r] + bias;
    }
  }
}

// ---------------------------------------------------------------------------
// ws (44 MB): Q 0 | K 8388608 | Vt 16777216 | Ap 25165824 | Wp1 33554432 |
//             Wp2 35127296 | Xp 35651584 .. 44040192
// ---------------------------------------------------------------------------
extern "C" void kernel_launch(void* const* d_in, const int* in_sizes, int n_in,
                              void* d_out, int out_size, void* d_ws,
                              size_t ws_size, hipStream_t stream) {
  const float* x = (const float*)d_in[0];
  const float* w_qkv = (const float*)d_in[1];
  const float* b_qkv = (const float*)d_in[2];
  const float* w_out = (const float*)d_in[3];
  const float* b_out = (const float*)d_in[4];
  float* out = (float*)d_out;

  char* ws = (char*)d_ws;
  bf16* Q = (bf16*)(ws + 0);
  bf16* K = (bf16*)(ws + 8388608);
  bf16* Vt = (bf16*)(ws + 16777216);
  bf16* Ap = (bf16*)(ws + 25165824);
  bf16* Wp1 = (bf16*)(ws + 33554432);
  bf16* Wp2 = (bf16*)(ws + 35127296);
  bf16* Xp = (bf16*)(ws + 35651584);

  cvt_pack_x<<<dim3(128, 8), 256, 0, stream>>>(x, Xp);
  transpose_pack_w<<<dim3(8, 24), 256, 0, stream>>>(w_qkv, Wp1, 1536, 8);
  transpose_pack_w<<<dim3(8, 8), 256, 0, stream>>>(w_out, Wp2, 512, 8);
  qkv_gemm<<<dim3(128, 24), 256, 0, stream>>>(Xp, Wp1, b_qkv, Q, K, Vt);
  flash_attn<<<dim3(64, 16), 256, 0, stream>>>(Q, K, Vt, Ap);
  out_gemm<<<dim3(128, 8), 256, 0, stream>>>(Ap, Wp2, b_out, out);
}

// Round 19
// 217.306 us; speedup vs baseline: 3.1592x; 1.1252x over previous
//
#include <hip/hip_runtime.h>

typedef __bf16 bf16;
typedef __bf16 bf16x8 __attribute__((ext_vector_type(8)));
typedef float f32x4 __attribute__((ext_vector_type(4)));

#define MFMA16(a, b, c) __builtin_amdgcn_mfma_f32_16x16x32_bf16((a), (b), (c), 0, 0, 0)

static __device__ __forceinline__ bf16x8 ldg8(const bf16* p) {
  return *(const bf16x8*)p;
}

// ===========================================================================
// Established: 5 fp32 inputs, FP32 output, ws >= 61.4MB (r14). Ladder:
// 803 -> 675 -> 365 (coalesced+swizzle) -> 258 (packed GEMMs) -> 246 -> 244.
// flash 135us is LDS-BW-bound: 24KB/wave/tile vs 128B/cyc/CU port (~61%).
// This round: 32 Q rows per wave (B-frags shared across 2 m-tiles) cuts LDS
// bytes/work 42%; KV-split grid (r13-proven partials+combine) keeps 1024
// blocks = 4/CU. PV-deferral dropped (was +4%) to fit LDS in 34.8KB.
// ===========================================================================

__global__ __launch_bounds__(256) void cvt_pack_x(const float* __restrict__ x,
                                                  bf16* __restrict__ Xp) {
  int mt = blockIdx.x, kc = blockIdx.y;
  int row = threadIdx.x >> 4;
  int c4 = (threadIdx.x & 15) * 4;
  bf16* tile = Xp + ((size_t)mt * 8 + kc) * 4096;
#pragma unroll
  for (int i = 0; i < 4; i++) {
    int r = i * 16 + row;
    const float* src = x + (size_t)(mt * 64 + r) * 512 + kc * 64 + c4;
    float4 v = *(const float4*)src;
    bf16* d = tile + r * 64 + c4;
    d[0] = (bf16)v.x; d[1] = (bf16)v.y; d[2] = (bf16)v.z; d[3] = (bf16)v.w;
  }
}

__global__ __launch_bounds__(256) void transpose_pack_w(const float* __restrict__ W,
                                                        bf16* __restrict__ Wp,
                                                        int N, int KC) {
  __shared__ bf16 tile[64][65];
  int kc = blockIdx.x, nt = blockIdx.y;
  int c = threadIdx.x & 63;
  int r4 = threadIdx.x >> 6;
#pragma unroll
  for (int i = 0; i < 16; i++) {
    int r = r4 * 16 + i;
    tile[r][c] = (bf16)W[(size_t)(kc * 64 + r) * N + nt * 64 + c];
  }
  __syncthreads();
  bf16* dst = Wp + ((size_t)nt * KC + kc) * 4096;
#pragma unroll
  for (int i = 0; i < 16; i++) {
    int r = r4 * 16 + i;
    dst[r * 64 + c] = tile[c][r];
  }
}

// ---------------------------------------------------------------------------
// Packed-tile GEMM core (r16-proven).
// ---------------------------------------------------------------------------
__device__ __forceinline__ void gemm_core_packed(const bf16* __restrict__ Ap,
                                                 const bf16* __restrict__ Bp,
                                                 int KC, bf16* Atile, bf16* Btile,
                                                 int tid, int wave, int l16,
                                                 int quad, f32x4 acc[4]) {
  for (int kc = 0; kc < KC; kc++) {
    __syncthreads();
    const bf16* ag = Ap + (size_t)kc * 4096;
    const bf16* bg = Bp + (size_t)kc * 4096;
#pragma unroll
    for (int rnd = 0; rnd < 2; rnd++) {
      int e = (rnd * 256 + tid) * 8;
      int row = e >> 6;
      int c16 = (e & 63) >> 3;
      int unit = row * 8 + (c16 ^ (row & 7));
      *(bf16x8*)&Atile[unit * 8] = ldg8(ag + e);
      *(bf16x8*)&Btile[unit * 8] = ldg8(bg + e);
    }
    __syncthreads();

    int ar = wave * 16 + l16;
    bf16x8 a0 = *(const bf16x8*)&Atile[(ar * 8 + (quad ^ (ar & 7))) * 8];
    bf16x8 a1 = *(const bf16x8*)&Atile[(ar * 8 + ((4 + quad) ^ (ar & 7))) * 8];
#pragma unroll
    for (int ct = 0; ct < 4; ct++) {
      int n = ct * 16 + l16;
      bf16x8 b0 = *(const bf16x8*)&Btile[(n * 8 + (quad ^ (n & 7))) * 8];
      bf16x8 b1 = *(const bf16x8*)&Btile[(n * 8 + ((4 + quad) ^ (n & 7))) * 8];
      acc[ct] = MFMA16(a0, b0, acc[ct]);
      acc[ct] = MFMA16(a1, b1, acc[ct]);
    }
  }
}

// ---------------------------------------------------------------------------
// QKV projection. Q pre-scaled by 0.125 (exact pow2). Q,K:[bh][n][d]; V tiled
// [bh][n>>6][d][n&63].
// ---------------------------------------------------------------------------
__global__ __launch_bounds__(256) void qkv_gemm(const bf16* __restrict__ Xp,
                                                const bf16* __restrict__ Wp1,
                                                const float* __restrict__ bqkv,
                                                bf16* __restrict__ Q,
                                                bf16* __restrict__ Kh,
                                                bf16* __restrict__ Vt) {
  int mt = blockIdx.x, nt = blockIdx.y;
  int tid = threadIdx.x;
  int wave = tid >> 6, lane = tid & 63;
  int l16 = lane & 15, quad = lane >> 4;

  __shared__ __align__(16) bf16 Atile[4096];
  __shared__ __align__(16) bf16 Btile[4096];

  f32x4 acc[4] = {};
  gemm_core_packed(Xp + (size_t)mt * 8 * 4096, Wp1 + (size_t)nt * 8 * 4096, 8,
                   Atile, Btile, tid, wave, l16, quad, acc);

#pragma unroll
  for (int ct = 0; ct < 4; ct++) {
    int c = nt * 64 + ct * 16 + l16;
    float bias = bqkv[c];
    int which = c >> 9, inner = c & 511;
    int h = inner >> 6, d = inner & 63;
#pragma unroll
    for (int r = 0; r < 4; r++) {
      int m = mt * 64 + wave * 16 + quad * 4 + r;
      int b = m >> 12, n = m & 4095;
      int bh = b * 8 + h;
      float v = acc[ct][r] + bias;
      if (which == 0)
        Q[((size_t)bh * 4096 + n) * 64 + d] = (bf16)(v * 0.125f);
      else if (which == 1)
        Kh[((size_t)bh * 4096 + n) * 64 + d] = (bf16)v;
      else
        Vt[(((size_t)bh * 64 + (n >> 6)) * 64 + d) * 64 + (n & 63)] = (bf16)v;
    }
  }
}

// ---------------------------------------------------------------------------
// flash_partial: grid (32 strip128, 16 bh, 2 half), block 256 = 4 waves.
// Each wave: 32 Q rows (2 m-tiles, B-frags shared), KV range half*2048.
// Reg-prefetch staging into swizzled LDS (r15-proven). Constant-max softmax.
// Partials: o (bf16 128x64/block) + l (fp32 128/block) to global.
// ---------------------------------------------------------------------------
__global__ __launch_bounds__(256, 4) void flash_partial(const bf16* __restrict__ Q,
                                                        const bf16* __restrict__ K,
                                                        const bf16* __restrict__ Vt,
                                                        bf16* __restrict__ Opart,
                                                        float* __restrict__ Lpart) {
  int strip = blockIdx.x, bh = blockIdx.y, half = blockIdx.z;
  int tid = threadIdx.x;
  int wave = tid >> 6, lane = tid & 63;
  int l16 = lane & 15, quad = lane >> 4;

  const bf16* Qh = Q + (size_t)bh * 4096 * 64;
  const bf16* Kg = K + ((size_t)bh * 4096 + half * 2048) * 64;
  const bf16* Vg = Vt + (size_t)bh * 64 * 4096 + (size_t)half * 2048 * 64;

  __shared__ __align__(16) bf16 Klds[4096];
  __shared__ __align__(16) bf16 Vlds[4096];
  __shared__ __align__(16) bf16 P[4][32][72];

  int qbase = strip * 128 + wave * 32;
  bf16x8 aq[2][2];
#pragma unroll
  for (int mt = 0; mt < 2; mt++) {
    const bf16* qr = Qh + (size_t)(qbase + mt * 16 + l16) * 64;
    aq[mt][0] = ldg8(qr + quad * 8);
    aq[mt][1] = ldg8(qr + 32 + quad * 8);
  }

  f32x4 o[2][4] = {};
  float l_lane[2][4] = {};

  int e0 = tid * 8, e1 = (256 + tid) * 8;
  int r0 = e0 >> 6, r1 = e1 >> 6;
  int u0 = r0 * 8 + (((e0 & 63) >> 3) ^ (r0 & 7));
  int u1 = r1 * 8 + (((e1 & 63) >> 3) ^ (r1 & 7));

  bf16x8 kp0 = ldg8(Kg + e0), kp1 = ldg8(Kg + e1);
  bf16x8 vp0 = ldg8(Vg + e0), vp1 = ldg8(Vg + e1);

  for (int kb = 0; kb < 2048; kb += 64) {
    __syncthreads();
    *(bf16x8*)&Klds[u0 * 8] = kp0;
    *(bf16x8*)&Klds[u1 * 8] = kp1;
    *(bf16x8*)&Vlds[u0 * 8] = vp0;
    *(bf16x8*)&Vlds[u1 * 8] = vp1;
    __syncthreads();

    if (kb + 64 < 2048) {
      const bf16* kg = Kg + (size_t)(kb + 64) * 64;
      const bf16* vg = Vg + (size_t)(kb + 64) * 64;
      kp0 = ldg8(kg + e0);
      kp1 = ldg8(kg + e1);
      vp0 = ldg8(vg + e0);
      vp1 = ldg8(vg + e1);
    }

    // ---- S = Q K^T for both m-tiles; B-frags read once ----
    f32x4 s[2][4] = {};
#pragma unroll
    for (int ct = 0; ct < 4; ct++) {
      int n = ct * 16 + l16;
      bf16x8 b0 = *(const bf16x8*)&Klds[(n * 8 + (quad ^ (n & 7))) * 8];
      bf16x8 b1 = *(const bf16x8*)&Klds[(n * 8 + ((4 + quad) ^ (n & 7))) * 8];
#pragma unroll
      for (int mt = 0; mt < 2; mt++) {
        s[mt][ct] = MFMA16(aq[mt][0], b0, s[mt][ct]);
        s[mt][ct] = MFMA16(aq[mt][1], b1, s[mt][ct]);
      }
    }
    // ---- p = exp(s); accumulate l; write P (C-layout, per-wave) ----
#pragma unroll
    for (int mt = 0; mt < 2; mt++)
#pragma unroll
      for (int ct = 0; ct < 4; ct++)
#pragma unroll
        for (int r = 0; r < 4; r++) {
          float p = __expf(s[mt][ct][r]);
          l_lane[mt][r] += p;
          P[wave][mt * 16 + quad * 4 + r][ct * 16 + l16] = (bf16)p;
        }
    // ---- O += P V (V-frags shared across m-tiles) ----
#pragma unroll
    for (int mt = 0; mt < 2; mt++) {
      bf16x8 ap0 = ldg8(&P[wave][mt * 16 + l16][quad * 8]);
      bf16x8 ap1 = ldg8(&P[wave][mt * 16 + l16][32 + quad * 8]);
#pragma unroll
      for (int ct = 0; ct < 4; ct++) {
        int d = ct * 16 + l16;
        bf16x8 bv0 = *(const bf16x8*)&Vlds[(d * 8 + (quad ^ (d & 7))) * 8];
        bf16x8 bv1 = *(const bf16x8*)&Vlds[(d * 8 + ((4 + quad) ^ (d & 7))) * 8];
        o[mt][ct] = MFMA16(ap0, bv0, o[mt][ct]);
        o[mt][ct] = MFMA16(ap1, bv1, o[mt][ct]);
      }
    }
  }

  // ---- epilogue: partial o (bf16) + l (fp32) ----
  size_t u = ((size_t)half * 16 + bh) * 32 + strip;
  bf16* op = Opart + u * 8192;
#pragma unroll
  for (int mt = 0; mt < 2; mt++) {
    float lrow[4];
#pragma unroll
    for (int r = 0; r < 4; r++) {
      float l = l_lane[mt][r];
#pragma unroll
      for (int off = 1; off < 16; off <<= 1) l += __shfl_xor(l, off);
      lrow[r] = l;
    }
#pragma unroll
    for (int ct = 0; ct < 4; ct++)
#pragma unroll
      for (int r = 0; r < 4; r++)
        op[(wave * 32 + mt * 16 + quad * 4 + r) * 64 + ct * 16 + l16] =
            (bf16)o[mt][ct][r];
    if (l16 == 0) {
#pragma unroll
      for (int r = 0; r < 4; r++)
        Lpart[u * 128 + wave * 32 + mt * 16 + quad * 4 + r] = lrow[r];
    }
  }
}

// ---------------------------------------------------------------------------
// flash_combine: Ap(packed) = (o0+o1)/(l0+l1). Grid (64 qt64, 16 bh).
// ---------------------------------------------------------------------------
__global__ __launch_bounds__(256) void flash_combine(const bf16* __restrict__ Opart,
                                                     const float* __restrict__ Lpart,
                                                     bf16* __restrict__ Ap) {
  int qt = blockIdx.x, bh = blockIdx.y;
  int col = threadIdx.x & 63;
  int rg = threadIdx.x >> 6;
  int strip = qt >> 1;
  int rbase = (qt & 1) * 64;
  size_t u0 = (size_t)bh * 32 + strip;
  size_t u1 = ((size_t)16 + bh) * 32 + strip;
  int b = bh >> 3, h = bh & 7;
  bf16* apt = Ap + (((size_t)(b * 64 + qt)) * 8 + h) * 4096;
#pragma unroll
  for (int i = 0; i < 16; i++) {
    int r64 = rg * 16 + i;
    int row = rbase + r64;
    float o0 = (float)Opart[u0 * 8192 + row * 64 + col];
    float o1 = (float)Opart[u1 * 8192 + row * 64 + col];
    float ls = Lpart[u0 * 128 + row] + Lpart[u1 * 128 + row];
    apt[r64 * 64 + col] = (bf16)((o0 + o1) / ls);
  }
}

// ---------------------------------------------------------------------------
// Output projection: Ap(packed) @ Wp2 -> FP32 out.
// ---------------------------------------------------------------------------
__global__ __launch_bounds__(256) void out_gemm(const bf16* __restrict__ Ap,
                                                const bf16* __restrict__ Wp2,
                                                const float* __restrict__ bout,
                                                float* __restrict__ Out) {
  int mt = blockIdx.x, nt = blockIdx.y;
  int tid = threadIdx.x;
  int wave = tid >> 6, lane = tid & 63;
  int l16 = lane & 15, quad = lane >> 4;

  __shared__ __align__(16) bf16 Atile[4096];
  __shared__ __align__(16) bf16 Btile[4096];

  f32x4 acc[4] = {};
  gemm_core_packed(Ap + (size_t)mt * 8 * 4096, Wp2 + (size_t)nt * 8 * 4096, 8,
                   Atile, Btile, tid, wave, l16, quad, acc);

#pragma unroll
  for (int ct = 0; ct < 4; ct++) {
    int c = nt * 64 + ct * 16 + l16;
    float bias = bout[c];
#pragma unroll
    for (int r = 0; r < 4; r++) {
      int m = mt * 64 + wave * 16 + quad * 4 + r;
      Out[(size_t)m * 512 + c] = acc[ct][r] + bias;
    }
  }
}

// ---------------------------------------------------------------------------
// ws: Q 0 | K 8388608 | Vt 16777216 | Ap 25165824 | Wp1 33554432 |
//     Wp2 35127296 | Xp 35651584 | Opart 44040192 | Lpart 60817408 (.52MB)
// ---------------------------------------------------------------------------
extern "C" void kernel_launch(void* const* d_in, const int* in_sizes, int n_in,
                              void* d_out, int out_size, void* d_ws,
                              size_t ws_size, hipStream_t stream) {
  const float* x = (const float*)d_in[0];
  const float* w_qkv = (const float*)d_in[1];
  const float* b_qkv = (const float*)d_in[2];
  const float* w_out = (const float*)d_in[3];
  const float* b_out = (const float*)d_in[4];
  float* out = (float*)d_out;

  char* ws = (char*)d_ws;
  bf16* Q = (bf16*)(ws + 0);
  bf16* K = (bf16*)(ws + 8388608);
  bf16* Vt = (bf16*)(ws + 16777216);
  bf16* Ap = (bf16*)(ws + 25165824);
  bf16* Wp1 = (bf16*)(ws + 33554432);
  bf16* Wp2 = (bf16*)(ws + 35127296);
  bf16* Xp = (bf16*)(ws + 35651584);
  bf16* Opart = (bf16*)(ws + 44040192);
  float* Lpart = (float*)(ws + 60817408);

  cvt_pack_x<<<dim3(128, 8), 256, 0, stream>>>(x, Xp);
  transpose_pack_w<<<dim3(8, 24), 256, 0, stream>>>(w_qkv, Wp1, 1536, 8);
  transpose_pack_w<<<dim3(8, 8), 256, 0, stream>>>(w_out, Wp2, 512, 8);
  qkv_gemm<<<dim3(128, 24), 256, 0, stream>>>(Xp, Wp1, b_qkv, Q, K, Vt);
  flash_partial<<<dim3(32, 16, 2), 256, 0, stream>>>(Q, K, Vt, Opart, Lpart);
  flash_combine<<<dim3(64, 16), 256, 0, stream>>>(Opart, Lpart, Ap);
  out_gemm<<<dim3(128, 8), 256, 0, stream>>>(Ap, Wp2, b_out, out);
}